// Round 12
// baseline (20048.924 us; speedup 1.0000x reference)
//
#include <hip/hip_runtime.h>

#define TSEQ 8192
#define DH   2048
#define DCAT 4096
#define ROWS 8      // hidden rows per seq workgroup (2048 / 256 WGs)
#define R3   32     // time rows per MFMA workgroup
#define WSTRIDE 68  // per-thread LDS weight block stride (floats); 272B
                    // == stride-4-dword bank pattern -> conflict-free b128

typedef __attribute__((ext_vector_type(8))) short bf16x8;
typedef __attribute__((ext_vector_type(4))) float f32x4;

__device__ inline short f2bf(float f) {  // RNE float->bf16
  unsigned int u = __float_as_uint(f);
  unsigned int r = (u + 0x7fffu + ((u >> 16) & 1u)) >> 16;
  return (short)r;
}

// ---------------------------------------------------------------------------
// Kernel 1: sentinel-init rows 1..8191 of d_out (h exchange buffer).
// Valid h values are sigmoid outputs (sign bit 0); sentinel -1.0f has sign 1.
// Runs every launch (harness does not re-poison between replays).
// ---------------------------------------------------------------------------
__global__ void init_sentinel_kernel(float* __restrict__ out) {
  const long long n4 = ((long long)(TSEQ - 1) * DH) / 4;  // rows 1..8191
  float4* p = (float4*)(out + DH);
  float4 s;
  s.x = s.y = s.z = s.w = -1.0f;
  const long long stride = (long long)gridDim.x * blockDim.x;
  for (long long i = (long long)blockIdx.x * blockDim.x + threadIdx.x; i < n4;
       i += stride)
    p[i] = s;
}

// ---------------------------------------------------------------------------
// Kernel 2: persistent sequential RNN — round-11 verified structure
// (1.66us/step, 0 bank conflicts) with two tail micro-fixes, isolated:
//   (a) red double-buffered by t&1 -> the trailing barrier is dropped
//       (one barrier/step). Safety: red[t&1] is rewritten at t+2 only after
//       barrier(t+1); wave 0 arrives at barrier(t+1) only after its step-t
//       tail read of red[t&1] -> no overlap.
//   (b) parallel tail: wave 0's 64 lanes each read red[wid][row], 3
//       shfl_xor over wid, lanes 0..7 add bias + sigmoid + publish.
//       Replaces the 8-thread serial tail (8 LDS reads + 7 adds each).
// Everything else byte-identical to round 11: 256 WGs x 512 thr; x half
// streams caption one step ahead; h half spins on agent-scope 8B loads of
// d_out row t-1 (columns spread 2KB apart, sign-bit flag, s_sleep(1));
// weights in LDS per-thread blocks at stride 68 (conflict-free).
// ---------------------------------------------------------------------------
__global__ __launch_bounds__(512, 1) void seq_kernel(
    const float* __restrict__ features, const float* __restrict__ caption,
    const float* __restrict__ W_h, const float* __restrict__ b_h,
    float* __restrict__ out) {
  const int tid  = threadIdx.x;
  const int i    = tid & 255;
  const int part = tid >> 8;
  const int rbase = blockIdx.x * ROWS;
  const int lane = tid & 63;
  const int wid  = tid >> 6;

  __shared__ float wlds[512 * WSTRIDE];   // 139264 B
  __shared__ float red[2][8][ROWS];

  // --- stage weights: thread's 64-float block, linear layout, stride 68 ---
#pragma unroll
  for (int r = 0; r < ROWS; ++r) {
    const float* wrow = W_h + (long long)(rbase + r) * DCAT + part * DH;
#pragma unroll
    for (int q = 0; q < 4; ++q) {
      float2 wv = *(const float2*)(wrow + q * 512 + i * 2);
      *(float2*)&wlds[tid * WSTRIDE + r * 8 + q * 2] = wv;
    }
  }
  const float bias = (tid < ROWS) ? b_h[rbase + tid] : 0.0f;
  __syncthreads();

  // x-half: preload caption row 0 (consumed at t=1)
  float an[8];
  if (part == 0) {
#pragma unroll
    for (int q = 0; q < 4; ++q) {
      float2 xv = *(const float2*)(caption + q * 512 + i * 2);
      an[2 * q]     = xv.x;
      an[2 * q + 1] = xv.y;
    }
  }

  for (int t = 1; t < TSEQ; ++t) {
    // issue weight ds_reads first (latency hides under the spin)
    float4 wr0[ROWS], wr1[ROWS];
#pragma unroll
    for (int r = 0; r < ROWS; ++r) {
      wr0[r] = *(const float4*)&wlds[tid * WSTRIDE + r * 8];
      wr1[r] = *(const float4*)&wlds[tid * WSTRIDE + r * 8 + 4];
    }

    float a[8];
    if (part == 0) {
      // consume prefetched row t-1; issue prefetch of row t (for t+1).
#pragma unroll
      for (int j = 0; j < 8; ++j) a[j] = an[j];
      const float* xn = caption + (long long)t * DH;
#pragma unroll
      for (int q = 0; q < 4; ++q) {
        float2 xv = *(const float2*)(xn + q * 512 + i * 2);
        an[2 * q]     = xv.x;
        an[2 * q + 1] = xv.y;
      }
    } else if (t == 1) {
      // h0 = features (input, no wait)
#pragma unroll
      for (int q = 0; q < 4; ++q) {
        float2 xv = *(const float2*)(features + q * 512 + i * 2);
        a[2 * q]     = xv.x;
        a[2 * q + 1] = xv.y;
      }
    } else {
      // spin on h_{t-1}: agent-scope 8B loads, columns spread 2KB apart
      const unsigned long long* hrow =
          (const unsigned long long*)(out + (long long)(t - 1) * DH);
      unsigned long long v[4];
      for (;;) {
        unsigned long long m = 0ull;
#pragma unroll
        for (int q = 0; q < 4; ++q) {
          v[q] = __hip_atomic_load(hrow + q * 256 + i, __ATOMIC_RELAXED,
                                   __HIP_MEMORY_SCOPE_AGENT);
          m |= v[q];
        }
        if ((m & 0x8000000080000000ull) == 0ull) break;
        __builtin_amdgcn_s_sleep(1);
      }
#pragma unroll
      for (int q = 0; q < 4; ++q) {
        a[2 * q]     = __uint_as_float((unsigned int)v[q]);
        a[2 * q + 1] = __uint_as_float((unsigned int)(v[q] >> 32));
      }
    }

    // --- per-thread partials: 8 rows x 8 cols ---
    float acc[ROWS];
#pragma unroll
    for (int r = 0; r < ROWS; ++r) {
      acc[r] = wr0[r].x * a[0] + wr0[r].y * a[1] + wr0[r].z * a[2] +
               wr0[r].w * a[3] + wr1[r].x * a[4] + wr1[r].y * a[5] +
               wr1[r].z * a[6] + wr1[r].w * a[7];
    }

    // --- folded wave reduction (verified rounds 1-11) ---
    float vv[8];
#pragma unroll
    for (int r = 0; r < ROWS; ++r) vv[r] = acc[r];
    {
      const bool up = lane & 1;
#pragma unroll
      for (int j = 0; j < 4; ++j) {
        float send  = up ? vv[j] : vv[j + 4];
        float other = __shfl_xor(send, 1, 64);
        vv[j] = (up ? vv[j + 4] : vv[j]) + other;
      }
    }
    {
      const bool up = lane & 2;
#pragma unroll
      for (int j = 0; j < 2; ++j) {
        float send  = up ? vv[j] : vv[j + 2];
        float other = __shfl_xor(send, 2, 64);
        vv[j] = (up ? vv[j + 2] : vv[j]) + other;
      }
    }
    {
      const bool up = lane & 4;
      float send  = up ? vv[0] : vv[1];
      float other = __shfl_xor(send, 4, 64);
      vv[0] = (up ? vv[1] : vv[0]) + other;
    }
    float v = vv[0];
    v += __shfl_xor(v, 8, 64);
    v += __shfl_xor(v, 16, 64);
    v += __shfl_xor(v, 32, 64);
    if (lane < 8) {
      const int row = ((lane & 1) << 2) | (lane & 2) | ((lane >> 2) & 1);
      red[t & 1][wid][row] = v;
    }
    __syncthreads();

    // --- parallel tail on wave 0: 1 LDS read + 3 shuffles, lanes 0..7 pub ---
    if (tid < 64) {
      float s = red[t & 1][tid >> 3][tid & 7];
      s += __shfl_xor(s, 8, 64);
      s += __shfl_xor(s, 16, 64);
      s += __shfl_xor(s, 32, 64);
      if (tid < ROWS) {
        float h = 1.0f / (1.0f + __expf(-(s + bias)));
        __hip_atomic_store(
            (unsigned int*)(out + (long long)t * DH + rbase + tid),
            __float_as_uint(h), __ATOMIC_RELAXED, __HIP_MEMORY_SCOPE_AGENT);
      }
    }
    // no trailing barrier: red is double-buffered by t&1 (safety in header)
  }
}

// ---------------------------------------------------------------------------
// Kernel 3: output projection via bf16 MFMA, IN PLACE on d_out (verified).
// WG owns R3=32 time-rows; stages them as bf16 in LDS (128 KB, XOR-swizzled
// both sides); W_o B-frags converted f32->bf16 on the fly. Row 0=caption[0].
// ---------------------------------------------------------------------------
__global__ __launch_bounds__(256, 1) void out_mfma_kernel(
    float* __restrict__ out, const float* __restrict__ W_o,
    const float* __restrict__ b_o, const float* __restrict__ caption) {
  __shared__ __align__(16) short hs[R3 * 2048];  // exactly 128 KiB
  const int tid  = threadIdx.x;
  const int lane = tid & 63;
  const int wv   = tid >> 6;
  const long long t0 = (long long)blockIdx.x * R3;
  const int r16  = lane & 15;
  const int kgrp = (lane >> 4) * 8;

  for (int idx = tid; idx < R3 * 256; idx += 256) {
    const int row = idx >> 8;
    const int c8  = idx & 255;
    const float* src = out + (t0 + row) * DH + c8 * 8;
    float4 va = *(const float4*)src;
    float4 vb = *(const float4*)(src + 4);
    bf16x8 h8;
    h8[0] = f2bf(va.x); h8[1] = f2bf(va.y); h8[2] = f2bf(va.z); h8[3] = f2bf(va.w);
    h8[4] = f2bf(vb.x); h8[5] = f2bf(vb.y); h8[6] = f2bf(vb.z); h8[7] = f2bf(vb.w);
    *(bf16x8*)&hs[row * 2048 + ((c8 * 8) ^ ((row & 7) << 3))] = h8;
  }
  __syncthreads();

  const int sw0 = (r16 & 7) << 3;

  for (int half = 0; half < 4; ++half) {
    const int n0 = wv * 512 + half * 128;
    f32x4 acc0[8], acc1[8];
#pragma unroll
    for (int j = 0; j < 8; ++j) {
      acc0[j] = (f32x4){0.f, 0.f, 0.f, 0.f};
      acc1[j] = (f32x4){0.f, 0.f, 0.f, 0.f};
    }
    for (int k0 = 0; k0 < DH; k0 += 32) {
      const int kofs = (k0 + kgrp) ^ sw0;
      bf16x8 a0 = *(const bf16x8*)&hs[r16 * 2048 + kofs];
      bf16x8 a1 = *(const bf16x8*)&hs[(16 + r16) * 2048 + kofs];
#pragma unroll
      for (int j = 0; j < 8; ++j) {
        const float* wp =
            W_o + (long long)(n0 + j * 16 + r16) * DH + k0 + kgrp;
        float4 wa = *(const float4*)wp;
        float4 wb = *(const float4*)(wp + 4);
        bf16x8 bfr;
        bfr[0] = f2bf(wa.x); bfr[1] = f2bf(wa.y);
        bfr[2] = f2bf(wa.z); bfr[3] = f2bf(wa.w);
        bfr[4] = f2bf(wb.x); bfr[5] = f2bf(wb.y);
        bfr[6] = f2bf(wb.z); bfr[7] = f2bf(wb.w);
        acc0[j] = __builtin_amdgcn_mfma_f32_16x16x32_bf16(a0, bfr, acc0[j], 0, 0, 0);
        acc1[j] = __builtin_amdgcn_mfma_f32_16x16x32_bf16(a1, bfr, acc1[j], 0, 0, 0);
      }
    }
#pragma unroll
    for (int j = 0; j < 8; ++j) {
      const int n = n0 + j * 16 + r16;
      const float bo = b_o[n];
#pragma unroll
      for (int r = 0; r < 4; ++r) {
        const long long row0 = t0 + (lane >> 4) * 4 + r;
        float v0 = 1.0f / (1.0f + __expf(-(acc0[j][r] + bo)));
        if (row0 == 0) v0 = caption[n];  // output[0] = caption[0]
        out[row0 * DH + n] = v0;
        const long long row1 = t0 + 16 + (lane >> 4) * 4 + r;
        float v1 = 1.0f / (1.0f + __expf(-(acc1[j][r] + bo)));
        out[row1 * DH + n] = v1;
      }
    }
  }
}

// ---------------------------------------------------------------------------
extern "C" void kernel_launch(void* const* d_in, const int* in_sizes, int n_in,
                              void* d_out, int out_size, void* d_ws,
                              size_t ws_size, hipStream_t stream) {
  const float* features = (const float*)d_in[0];
  const float* caption  = (const float*)d_in[1];
  const float* W_h      = (const float*)d_in[2];
  const float* b_h      = (const float*)d_in[3];
  const float* W_o      = (const float*)d_in[4];
  const float* b_o      = (const float*)d_in[5];
  float* out = (float*)d_out;

  hipLaunchKernelGGL(init_sentinel_kernel, dim3(2048), dim3(256), 0, stream,
                     out);
  hipLaunchKernelGGL(seq_kernel, dim3(DH / ROWS), dim3(512), 0, stream,
                     features, caption, W_h, b_h, out);
  hipLaunchKernelGGL(out_mfma_kernel, dim3(TSEQ / R3), dim3(256), 0, stream,
                     out, W_o, b_o, caption);
}

// Round 13
// 10984.336 us; speedup vs baseline: 1.8252x; 1.8252x over previous
//
#include <hip/hip_runtime.h>

#define TSEQ 8192
#define DH   2048
#define DCAT 4096
#define ROWS 8      // hidden rows per seq workgroup (2048 / 256 WGs)
#define R3   32     // time rows per MFMA workgroup
#define WSTRIDE 68  // per-thread LDS weight block stride (floats); 272B
                    // == stride-4-dword bank pattern -> conflict-free b128

typedef __attribute__((ext_vector_type(8))) short bf16x8;
typedef __attribute__((ext_vector_type(4))) float f32x4;

__device__ inline short f2bf(float f) {  // RNE float->bf16
  unsigned int u = __float_as_uint(f);
  unsigned int r = (u + 0x7fffu + ((u >> 16) & 1u)) >> 16;
  return (short)r;
}

// ---------------------------------------------------------------------------
// Kernel 1: sentinel-init rows 1..8191 of d_out (h exchange buffer).
// Valid h values are sigmoid outputs (sign bit 0); sentinel -1.0f has sign 1.
// Runs every launch (harness does not re-poison between replays).
// ---------------------------------------------------------------------------
__global__ void init_sentinel_kernel(float* __restrict__ out) {
  const long long n4 = ((long long)(TSEQ - 1) * DH) / 4;  // rows 1..8191
  float4* p = (float4*)(out + DH);
  float4 s;
  s.x = s.y = s.z = s.w = -1.0f;
  const long long stride = (long long)gridDim.x * blockDim.x;
  for (long long i = (long long)blockIdx.x * blockDim.x + threadIdx.x; i < n4;
       i += stride)
    p[i] = s;
}

// ---------------------------------------------------------------------------
// Kernel 2: persistent sequential RNN — round-11 verified structure
// (1.66us/step, 0 conflicts, 12.75ms total best) with ONE isolated change:
// the parallel tail (wave 0: 1 LDS read + 3 shfl_xor instead of the 8-thread
// serial 8-read tail).
// BOTH barriers are kept. Round-12 post-mortem: dropping the trailing
// barrier desynchronized the WG's waves -> h-half spun whole steps ahead of
// the tail-burdened wave 0 -> poll rounds on unpublished (sentinel-cold)
// rows multiplied -> FETCH_SIZE 540->1007 MB, 45% slower. The lockstep
// trailing barrier is load-bearing: it minimizes spin rounds, which are the
// dominant system cost (same lesson as r5/r7).
// Structure: 256 WGs x 512 thr; WG g owns rows [8g,8g+8); x half streams
// caption one step ahead; h half spins on agent-scope 8B loads of d_out row
// t-1 (columns spread 2KB apart, sign-bit flag, s_sleep(1)); weights in LDS
// per-thread blocks at stride 68 (conflict-free); folded wave reduce.
// ---------------------------------------------------------------------------
__global__ __launch_bounds__(512, 1) void seq_kernel(
    const float* __restrict__ features, const float* __restrict__ caption,
    const float* __restrict__ W_h, const float* __restrict__ b_h,
    float* __restrict__ out) {
  const int tid  = threadIdx.x;
  const int i    = tid & 255;
  const int part = tid >> 8;
  const int rbase = blockIdx.x * ROWS;
  const int lane = tid & 63;
  const int wid  = tid >> 6;

  __shared__ float wlds[512 * WSTRIDE];   // 139264 B
  __shared__ float red[2][8][ROWS];

  // --- stage weights: thread's 64-float block, linear layout, stride 68 ---
#pragma unroll
  for (int r = 0; r < ROWS; ++r) {
    const float* wrow = W_h + (long long)(rbase + r) * DCAT + part * DH;
#pragma unroll
    for (int q = 0; q < 4; ++q) {
      float2 wv = *(const float2*)(wrow + q * 512 + i * 2);
      *(float2*)&wlds[tid * WSTRIDE + r * 8 + q * 2] = wv;
    }
  }
  const float bias = (tid < ROWS) ? b_h[rbase + tid] : 0.0f;
  __syncthreads();

  // x-half: preload caption row 0 (consumed at t=1)
  float an[8];
  if (part == 0) {
#pragma unroll
    for (int q = 0; q < 4; ++q) {
      float2 xv = *(const float2*)(caption + q * 512 + i * 2);
      an[2 * q]     = xv.x;
      an[2 * q + 1] = xv.y;
    }
  }

  for (int t = 1; t < TSEQ; ++t) {
    // issue weight ds_reads first (latency hides under the spin)
    float4 wr0[ROWS], wr1[ROWS];
#pragma unroll
    for (int r = 0; r < ROWS; ++r) {
      wr0[r] = *(const float4*)&wlds[tid * WSTRIDE + r * 8];
      wr1[r] = *(const float4*)&wlds[tid * WSTRIDE + r * 8 + 4];
    }

    float a[8];
    if (part == 0) {
      // consume prefetched row t-1; issue prefetch of row t (for t+1).
#pragma unroll
      for (int j = 0; j < 8; ++j) a[j] = an[j];
      const float* xn = caption + (long long)t * DH;
#pragma unroll
      for (int q = 0; q < 4; ++q) {
        float2 xv = *(const float2*)(xn + q * 512 + i * 2);
        an[2 * q]     = xv.x;
        an[2 * q + 1] = xv.y;
      }
    } else if (t == 1) {
      // h0 = features (input, no wait)
#pragma unroll
      for (int q = 0; q < 4; ++q) {
        float2 xv = *(const float2*)(features + q * 512 + i * 2);
        a[2 * q]     = xv.x;
        a[2 * q + 1] = xv.y;
      }
    } else {
      // spin on h_{t-1}: agent-scope 8B loads, columns spread 2KB apart
      const unsigned long long* hrow =
          (const unsigned long long*)(out + (long long)(t - 1) * DH);
      unsigned long long v[4];
      for (;;) {
        unsigned long long m = 0ull;
#pragma unroll
        for (int q = 0; q < 4; ++q) {
          v[q] = __hip_atomic_load(hrow + q * 256 + i, __ATOMIC_RELAXED,
                                   __HIP_MEMORY_SCOPE_AGENT);
          m |= v[q];
        }
        if ((m & 0x8000000080000000ull) == 0ull) break;
        __builtin_amdgcn_s_sleep(1);
      }
#pragma unroll
      for (int q = 0; q < 4; ++q) {
        a[2 * q]     = __uint_as_float((unsigned int)v[q]);
        a[2 * q + 1] = __uint_as_float((unsigned int)(v[q] >> 32));
      }
    }

    // --- per-thread partials: 8 rows x 8 cols ---
    float acc[ROWS];
#pragma unroll
    for (int r = 0; r < ROWS; ++r) {
      acc[r] = wr0[r].x * a[0] + wr0[r].y * a[1] + wr0[r].z * a[2] +
               wr0[r].w * a[3] + wr1[r].x * a[4] + wr1[r].y * a[5] +
               wr1[r].z * a[6] + wr1[r].w * a[7];
    }

    // --- folded wave reduction (verified rounds 1-12) ---
    float vv[8];
#pragma unroll
    for (int r = 0; r < ROWS; ++r) vv[r] = acc[r];
    {
      const bool up = lane & 1;
#pragma unroll
      for (int j = 0; j < 4; ++j) {
        float send  = up ? vv[j] : vv[j + 4];
        float other = __shfl_xor(send, 1, 64);
        vv[j] = (up ? vv[j + 4] : vv[j]) + other;
      }
    }
    {
      const bool up = lane & 2;
#pragma unroll
      for (int j = 0; j < 2; ++j) {
        float send  = up ? vv[j] : vv[j + 2];
        float other = __shfl_xor(send, 2, 64);
        vv[j] = (up ? vv[j + 2] : vv[j]) + other;
      }
    }
    {
      const bool up = lane & 4;
      float send  = up ? vv[0] : vv[1];
      float other = __shfl_xor(send, 4, 64);
      vv[0] = (up ? vv[1] : vv[0]) + other;
    }
    float v = vv[0];
    v += __shfl_xor(v, 8, 64);
    v += __shfl_xor(v, 16, 64);
    v += __shfl_xor(v, 32, 64);
    if (lane < 8) {
      const int row = ((lane & 1) << 2) | (lane & 2) | ((lane >> 2) & 1);
      red[t & 1][wid][row] = v;
    }
    __syncthreads();

    // --- parallel tail on wave 0: 1 LDS read + 3 shuffles, lanes 0..7 pub ---
    if (tid < 64) {
      float s = red[t & 1][tid >> 3][tid & 7];
      s += __shfl_xor(s, 8, 64);
      s += __shfl_xor(s, 16, 64);
      s += __shfl_xor(s, 32, 64);
      if (tid < ROWS) {
        float h = 1.0f / (1.0f + __expf(-(s + bias)));
        __hip_atomic_store(
            (unsigned int*)(out + (long long)t * DH + rbase + tid),
            __float_as_uint(h), __ATOMIC_RELAXED, __HIP_MEMORY_SCOPE_AGENT);
      }
    }
    __syncthreads();  // lockstep barrier — load-bearing (r12 post-mortem)
  }
}

// ---------------------------------------------------------------------------
// Kernel 3: output projection via bf16 MFMA, IN PLACE on d_out (verified).
// WG owns R3=32 time-rows; stages them as bf16 in LDS (128 KB, XOR-swizzled
// both sides); W_o B-frags converted f32->bf16 on the fly. Row 0=caption[0].
// ---------------------------------------------------------------------------
__global__ __launch_bounds__(256, 1) void out_mfma_kernel(
    float* __restrict__ out, const float* __restrict__ W_o,
    const float* __restrict__ b_o, const float* __restrict__ caption) {
  __shared__ __align__(16) short hs[R3 * 2048];  // exactly 128 KiB
  const int tid  = threadIdx.x;
  const int lane = tid & 63;
  const int wv   = tid >> 6;
  const long long t0 = (long long)blockIdx.x * R3;
  const int r16  = lane & 15;
  const int kgrp = (lane >> 4) * 8;

  for (int idx = tid; idx < R3 * 256; idx += 256) {
    const int row = idx >> 8;
    const int c8  = idx & 255;
    const float* src = out + (t0 + row) * DH + c8 * 8;
    float4 va = *(const float4*)src;
    float4 vb = *(const float4*)(src + 4);
    bf16x8 h8;
    h8[0] = f2bf(va.x); h8[1] = f2bf(va.y); h8[2] = f2bf(va.z); h8[3] = f2bf(va.w);
    h8[4] = f2bf(vb.x); h8[5] = f2bf(vb.y); h8[6] = f2bf(vb.z); h8[7] = f2bf(vb.w);
    *(bf16x8*)&hs[row * 2048 + ((c8 * 8) ^ ((row & 7) << 3))] = h8;
  }
  __syncthreads();

  const int sw0 = (r16 & 7) << 3;

  for (int half = 0; half < 4; ++half) {
    const int n0 = wv * 512 + half * 128;
    f32x4 acc0[8], acc1[8];
#pragma unroll
    for (int j = 0; j < 8; ++j) {
      acc0[j] = (f32x4){0.f, 0.f, 0.f, 0.f};
      acc1[j] = (f32x4){0.f, 0.f, 0.f, 0.f};
    }
    for (int k0 = 0; k0 < DH; k0 += 32) {
      const int kofs = (k0 + kgrp) ^ sw0;
      bf16x8 a0 = *(const bf16x8*)&hs[r16 * 2048 + kofs];
      bf16x8 a1 = *(const bf16x8*)&hs[(16 + r16) * 2048 + kofs];
#pragma unroll
      for (int j = 0; j < 8; ++j) {
        const float* wp =
            W_o + (long long)(n0 + j * 16 + r16) * DH + k0 + kgrp;
        float4 wa = *(const float4*)wp;
        float4 wb = *(const float4*)(wp + 4);
        bf16x8 bfr;
        bfr[0] = f2bf(wa.x); bfr[1] = f2bf(wa.y);
        bfr[2] = f2bf(wa.z); bfr[3] = f2bf(wa.w);
        bfr[4] = f2bf(wb.x); bfr[5] = f2bf(wb.y);
        bfr[6] = f2bf(wb.z); bfr[7] = f2bf(wb.w);
        acc0[j] = __builtin_amdgcn_mfma_f32_16x16x32_bf16(a0, bfr, acc0[j], 0, 0, 0);
        acc1[j] = __builtin_amdgcn_mfma_f32_16x16x32_bf16(a1, bfr, acc1[j], 0, 0, 0);
      }
    }
#pragma unroll
    for (int j = 0; j < 8; ++j) {
      const int n = n0 + j * 16 + r16;
      const float bo = b_o[n];
#pragma unroll
      for (int r = 0; r < 4; ++r) {
        const long long row0 = t0 + (lane >> 4) * 4 + r;
        float v0 = 1.0f / (1.0f + __expf(-(acc0[j][r] + bo)));
        if (row0 == 0) v0 = caption[n];  // output[0] = caption[0]
        out[row0 * DH + n] = v0;
        const long long row1 = t0 + 16 + (lane >> 4) * 4 + r;
        float v1 = 1.0f / (1.0f + __expf(-(acc1[j][r] + bo)));
        out[row1 * DH + n] = v1;
      }
    }
  }
}

// ---------------------------------------------------------------------------
extern "C" void kernel_launch(void* const* d_in, const int* in_sizes, int n_in,
                              void* d_out, int out_size, void* d_ws,
                              size_t ws_size, hipStream_t stream) {
  const float* features = (const float*)d_in[0];
  const float* caption  = (const float*)d_in[1];
  const float* W_h      = (const float*)d_in[2];
  const float* b_h      = (const float*)d_in[3];
  const float* W_o      = (const float*)d_in[4];
  const float* b_o      = (const float*)d_in[5];
  float* out = (float*)d_out;

  hipLaunchKernelGGL(init_sentinel_kernel, dim3(2048), dim3(256), 0, stream,
                     out);
  hipLaunchKernelGGL(seq_kernel, dim3(DH / ROWS), dim3(512), 0, stream,
                     features, caption, W_h, b_h, out);
  hipLaunchKernelGGL(out_mfma_kernel, dim3(TSEQ / R3), dim3(256), 0, stream,
                     out, W_o, b_o, caption);
}